// Round 6
// baseline (7543.713 us; speedup 1.0000x reference)
//
#include <hip/hip_runtime.h>

typedef __attribute__((ext_vector_type(8)))  short short8;
typedef __attribute__((ext_vector_type(4)))  float f32x4;
typedef __attribute__((ext_vector_type(16))) float f32x16;

#define L0    8192
#define LFIN  4612
#define PSKIP 3580   // L0 - LFIN

static const int DILS[39] = {
  1,2,4,8,16,32,64,128,256,512,
  1,2,4,8,16,32,64,128,256,512,
  1,2,4,8,16,32,64,128,256,512,
  1,2,4,8,16,32,64,128,256};

__constant__ int cDILS[39] = {
  1,2,4,8,16,32,64,128,256,512,
  1,2,4,8,16,32,64,128,256,512,
  1,2,4,8,16,32,64,128,256,512,
  1,2,4,8,16,32,64,128,256};

__device__ __forceinline__ unsigned short f2bf(float f) {
  unsigned u = __builtin_bit_cast(unsigned, f);
  u += 0x7fffu + ((u >> 16) & 1u);          // RNE
  return (unsigned short)(u >> 16);
}
__device__ __forceinline__ float bf2f(unsigned short h) {
  return __builtin_bit_cast(float, (unsigned)h << 16);
}

// ---------------- weight conversion f32 -> bf16 (once per call) ----------------
// Wd layout: [layer][co 256][k 256], k = tap*128 + ci  (tap0 @ p-d, tap1 @ p)
__global__ __launch_bounds__(256) void wconv_kernel(
    const float* __restrict__ dw, const float* __restrict__ rw,
    const float* __restrict__ sw, const float* __restrict__ ew,
    unsigned short* __restrict__ Wd, unsigned short* __restrict__ Wr,
    unsigned short* __restrict__ Ws, unsigned short* __restrict__ We)
{
  int e = blockIdx.x * 256 + threadIdx.x;
  const int ND = 39*65536, NR = 39*16384, NS = 39*32768, NE = 16384;
  if (e < ND) {
    int i = e >> 16, r = e & 65535;
    int co = r >> 8, k = r & 255;
    int tap = k >> 7, ci = k & 127;
    Wd[e] = f2bf(dw[(((size_t)i*256 + co)*128 + ci)*2 + tap]);
  } else if ((e -= ND) < NR) {
    Wr[e] = f2bf(rw[e]);
  } else if ((e -= NR) < NS) {
    Ws[e] = f2bf(sw[e]);
  } else if ((e -= NS) < NE) {
    We[e] = f2bf(ew[e]);
  }
}

// ---------------- per-batch global barrier (device-scope, XCD-mapping-independent) ----
__device__ __forceinline__ void gbar(unsigned* bar, int n, unsigned target, int tid) {
  __syncthreads();                       // drains vmcnt: all block stores in L2
  if (tid == 0) {
    __threadfence();                     // release: L2 writeback to coherence point
    atomicAdd(&bar[n], 1u);
    while (atomicAdd(&bar[n], 0u) < target) __builtin_amdgcn_s_sleep(8);
    __threadfence();                     // acquire: invalidate stale lines
  }
  __syncthreads();
}

// ---------------- gate f/g -> bf16 overlay into T0 (rows nb*32..) ----------------
__device__ __forceinline__ void gate_write(char* T0, const float* __restrict__ dbl,
    const f32x16& af, const f32x16& ag, int p, int w, int hi)
{
  #pragma unroll
  for (int q = 0; q < 4; ++q) {
    int rbase = 8*q + 4*hi;
    const float4 bf4 = *(const float4*)&dbl[32*w + rbase];
    const float4 bg4 = *(const float4*)&dbl[128 + 32*w + rbase];
    const float bfv[4] = {bf4.x, bf4.y, bf4.z, bf4.w};
    const float bgv[4] = {bg4.x, bg4.y, bg4.z, bg4.w};
    unsigned short gs[4];
    #pragma unroll
    for (int r = 0; r < 4; ++r) {
      float fv = af[4*q + r] + bfv[r];
      float gg = ag[4*q + r] + bgv[r];
      float th = 2.f * __builtin_amdgcn_rcpf(1.f + __expf(-2.f * fv)) - 1.f;
      float sg = __builtin_amdgcn_rcpf(1.f + __expf(-gg));
      gs[r] = f2bf(th * sg);
    }
    ushort4 gv; gv.x = gs[0]; gv.y = gs[1]; gv.z = gs[2]; gv.w = gs[3];
    int byte = (((p << 8) + ((32*w + rbase) << 1))) ^ ((p & 7) << 4);
    *(ushort4*)(T0 + byte) = gv;
  }
}

// ---------------- persistent fused kernel: start + 39 layers + end ----------------
// Block lb: batch n = lb&7, tile bx = lb>>3, positions [bx*64, bx*64+64).
// LDS: T0 [64p][128ci] bf16 swizzled (tap0 / gated overlay), HC [64p][128ci] (tap1 = own H).
// Skip accumulator: f32x16 sk[2][2] in VGPRs, MFMA C-in chained across all layers.
__global__ __launch_bounds__(256, 4) void wavenet_all(
    const float* __restrict__ x, const float* __restrict__ startw,
    const float* __restrict__ startb,
    const unsigned short* __restrict__ Wd, const float* __restrict__ dilb,
    const unsigned short* __restrict__ Wr, const float* __restrict__ resb,
    const unsigned short* __restrict__ Ws, const float* __restrict__ skipb,
    const unsigned short* __restrict__ We, const float* __restrict__ endb,
    unsigned short* __restrict__ Hg0, unsigned short* __restrict__ Hg1,
    float* __restrict__ out, unsigned* __restrict__ bar)
{
  __shared__ __align__(16) char LB[32768];
  __shared__ float sbs[256];
  char* T0 = LB;              // [64][128] bf16, row 256B, byte ^= (p&7)<<4
  char* HC = LB + 16384;      // [64][128] bf16, same swizzle

  const int tid = threadIdx.x;
  const int lb = blockIdx.x;
  const int n  = lb & 7;
  const int bx = lb >> 3;
  const int p0 = bx * 64;
  const bool doSkip = (p0 + 63) >= PSKIP;

  const int w  = tid >> 6, lane = tid & 63;
  const int ln = lane & 31, hi = lane >> 5;

  // ---- start conv 40->128 for own 64 positions; also fold skip-bias sum ----
  {
    float* xs = (float*)LB;   // [40][64] f32 (overlaps T0 only; HC untouched)
    for (int e = tid; e < 40*64; e += 256) {
      int ci = e >> 6, t = e & 63;
      xs[ci*64 + t] = x[((size_t)n*40 + ci)*L0 + p0 + t];
    }
    float s = 0.f;
    for (int i = 0; i < 39; ++i) s += skipb[i*256 + tid];
    sbs[tid] = s;
    __syncthreads();
    const int c = tid & 127, ph = tid >> 7;
    const float b0 = startb[c];
    #pragma unroll
    for (int half = 0; half < 2; ++half) {
      float acc[16];
      #pragma unroll
      for (int k = 0; k < 16; ++k) acc[k] = b0;
      for (int ci = 0; ci < 40; ++ci) {
        float wv = startw[c*40 + ci];
        #pragma unroll
        for (int k = 0; k < 16; ++k)
          acc[k] = fmaf(wv, xs[ci*64 + ph + 2*(16*half + k)], acc[k]);
      }
      #pragma unroll
      for (int k = 0; k < 16; ++k) {
        int p = ph + 2*(16*half + k);
        unsigned short hb = f2bf(acc[k]);
        *(unsigned short*)(HC + ((((p << 8) + (c << 1))) ^ ((p & 7) << 4))) = hb;
        Hg0[((size_t)n*L0 + p0 + p)*128 + c] = hb;
      }
    }
  }
  gbar(bar, n, 128u, tid);

  const f32x16 fz16 = {0.f};
  f32x16 sk[2][2] = {{fz16, fz16}, {fz16, fz16}};

  #pragma unroll 1
  for (int i = 0; i < 39; ++i) {
    if (i == 38 && !doSkip) break;       // non-skip blocks: H(38) unused by anyone
    const int d = cDILS[i];
    const unsigned short* __restrict__ Hcur = (i & 1) ? Hg1 : Hg0;
    unsigned short* __restrict__ Hnxt = (i & 1) ? Hg0 : Hg1;
    const unsigned short* __restrict__ Wdl = Wd + (size_t)i*65536;
    const unsigned short* __restrict__ Wrl = Wr + (size_t)i*16384;
    const unsigned short* __restrict__ Wsl = Ws + (size_t)i*32768;
    const float* __restrict__ dbl = dilb + i*256;
    const float* __restrict__ rbl = resb + i*128;

    // ---- stage tap0 (positions p0-d .. p0+63-d) into T0 ----
    #pragma unroll
    for (int it = 0; it < 4; ++it) {
      int e = it * 256 + tid;            // 0..1023
      int c8 = (e & 15) << 3;
      int p  = e >> 4;
      int gp = p0 + p - d; if (gp < 0) gp = 0;   // below-valid region: garbage, unused
      short8 v = *(const short8*)&Hcur[((size_t)n*L0 + gp)*128 + c8];
      *(short8*)(T0 + ((((p << 8) + (c8 << 1))) ^ ((p & 7) << 4))) = v;
    }
    __syncthreads();

    // ---- GEMM1 nb=0: D[256co regs][32p lanes], K=256 (tap0 from T0, tap1 from HC) ----
    f32x16 af = fz16, ag = fz16;
    #pragma unroll
    for (int ks = 0; ks < 16; ++ks) {
      const char* src = (ks < 8) ? T0 : HC;
      int kb = (ks & 7)*32 + hi*16;
      int p = ln;
      short8 B  = *(const short8*)(src + ((((p << 8) + kb)) ^ ((p & 7) << 4)));
      short8 Af = *(const short8*)&Wdl[(size_t)(32*w + ln)*256 + ks*16 + hi*8];
      short8 Ag = *(const short8*)&Wdl[(size_t)(128 + 32*w + ln)*256 + ks*16 + hi*8];
      af = __builtin_amdgcn_mfma_f32_32x32x16_bf16(Af, B, af, 0, 0, 0);
      ag = __builtin_amdgcn_mfma_f32_32x32x16_bf16(Ag, B, ag, 0, 0, 0);
    }
    __syncthreads();                     // all waves done reading rows 0..31
    gate_write(T0, dbl, af, ag, ln, w, hi);          // overlay rows 0..31

    // ---- GEMM1 nb=1 (rows 32..63 -- disjoint from the nb0 overlay) ----
    af = fz16; ag = fz16;
    #pragma unroll
    for (int ks = 0; ks < 16; ++ks) {
      const char* src = (ks < 8) ? T0 : HC;
      int kb = (ks & 7)*32 + hi*16;
      int p = 32 + ln;
      short8 B  = *(const short8*)(src + ((((p << 8) + kb)) ^ ((p & 7) << 4)));
      short8 Af = *(const short8*)&Wdl[(size_t)(32*w + ln)*256 + ks*16 + hi*8];
      short8 Ag = *(const short8*)&Wdl[(size_t)(128 + 32*w + ln)*256 + ks*16 + hi*8];
      af = __builtin_amdgcn_mfma_f32_32x32x16_bf16(Af, B, af, 0, 0, 0);
      ag = __builtin_amdgcn_mfma_f32_32x32x16_bf16(Ag, B, ag, 0, 0, 0);
    }
    __syncthreads();                     // all waves done reading rows 32..63
    gate_write(T0, dbl, af, ag, 32 + ln, w, hi);     // overlay rows 32..63
    __syncthreads();                     // gated tile complete

    // ---- skip GEMM: accumulate straight into persistent sk (C-in chain) ----
    if (doSkip) {
      #pragma unroll
      for (int t = 0; t < 2; ++t) {
        #pragma unroll
        for (int nb = 0; nb < 2; ++nb) {
          int p = nb*32 + ln;
          #pragma unroll
          for (int ks = 0; ks < 8; ++ks) {
            short8 A = *(const short8*)&Wsl[(size_t)(32*w + 128*t + ln)*128 + ks*16 + hi*8];
            short8 B = *(const short8*)(T0 + ((((p << 8) + ks*32 + hi*16)) ^ ((p & 7) << 4)));
            sk[t][nb] = __builtin_amdgcn_mfma_f32_32x32x16_bf16(A, B, sk[t][nb], 0, 0, 0);
          }
        }
      }
    }

    // ---- res GEMM + residual; update HC and publish H to global ----
    if (i < 38) {
      #pragma unroll
      for (int nb = 0; nb < 2; ++nb) {
        f32x16 acc = fz16;
        int pl = nb*32 + ln;
        #pragma unroll
        for (int ks = 0; ks < 8; ++ks) {
          short8 A = *(const short8*)&Wrl[(size_t)(32*w + ln)*128 + ks*16 + hi*8];
          short8 B = *(const short8*)(T0 + ((((pl << 8) + ks*32 + hi*16)) ^ ((pl & 7) << 4)));
          acc = __builtin_amdgcn_mfma_f32_32x32x16_bf16(A, B, acc, 0, 0, 0);
        }
        int p = p0 + pl;
        #pragma unroll
        for (int q = 0; q < 4; ++q) {
          int co = 32*w + 8*q + 4*hi;
          const float4 rb4 = *(const float4*)&rbl[co];
          int hbyte = (((pl << 8) + (co << 1))) ^ ((pl & 7) << 4);
          ushort4 hv = *(const ushort4*)(HC + hbyte);
          ushort4 hb;
          hb.x = f2bf(acc[4*q]   + rb4.x + bf2f(hv.x));
          hb.y = f2bf(acc[4*q+1] + rb4.y + bf2f(hv.y));
          hb.z = f2bf(acc[4*q+2] + rb4.z + bf2f(hv.z));
          hb.w = f2bf(acc[4*q+3] + rb4.w + bf2f(hv.w));
          *(ushort4*)(HC + hbyte) = hb;
          *(ushort4*)&Hnxt[((size_t)n*L0 + p)*128 + co] = hb;
        }
      }
      gbar(bar, n, 128u*(unsigned)(i + 2), tid);
    }
  }

  // ---- end: relu(skip + sum_bias) , 1x1 conv 256 -> 64, own 64 positions ----
  if (doSkip) {
    __syncthreads();                     // everyone done with T0/HC
    #pragma unroll
    for (int t = 0; t < 2; ++t) {
      #pragma unroll
      for (int nb = 0; nb < 2; ++nb) {
        int p = nb*32 + ln;
        #pragma unroll
        for (int q = 0; q < 4; ++q) {
          int co0 = 32*w + 128*t + 8*q + 4*hi;
          unsigned short gs[4];
          #pragma unroll
          for (int r = 0; r < 4; ++r) {
            float v = sk[t][nb][4*q + r] + sbs[co0 + r];
            gs[r] = f2bf(fmaxf(v, 0.f));
          }
          ushort4 gv; gv.x = gs[0]; gv.y = gs[1]; gv.z = gs[2]; gv.w = gs[3];
          *(ushort4*)(LB + ((((p << 9) + (co0 << 1))) ^ ((p & 7) << 4))) = gv;  // [64][256]
        }
      }
    }
    __syncthreads();

    const int lr = lane & 15, lg = lane >> 4;
    const f32x4 fz = {0.f, 0.f, 0.f, 0.f};
    f32x4 acc[4] = {fz, fz, fz, fz};
    #pragma unroll
    for (int ks = 0; ks < 8; ++ks) {
      short8 A = *(const short8*)&We[(size_t)(16*w + lr)*256 + ks*32 + lg*8];
      #pragma unroll
      for (int nb = 0; nb < 4; ++nb) {
        int p = nb*16 + lr;
        short8 B = *(const short8*)(LB + ((((p << 9) + ((ks*32 + lg*8) << 1))) ^ ((p & 7) << 4)));
        acc[nb] = __builtin_amdgcn_mfma_f32_16x16x32_bf16(A, B, acc[nb], 0, 0, 0);
      }
    }
    #pragma unroll
    for (int nb = 0; nb < 4; ++nb) {
      int p = p0 + nb*16 + lr;
      if (p >= PSKIP) {
        #pragma unroll
        for (int r = 0; r < 4; ++r) {
          int co = 16*w + lg*4 + r;
          out[((size_t)n*64 + co)*LFIN + (p - PSKIP)] = acc[nb][r] + endb[co];
        }
      }
    }
  }
}

// ================= fallback path (R3-proven kernels), used if cooperative launch fails =====

__global__ __launch_bounds__(256) void start_kernel(
    const float* __restrict__ x, const float* __restrict__ w,
    const float* __restrict__ b, unsigned short* __restrict__ H)
{
  __shared__ float xs[40][64];
  __shared__ float wl[128*41];
  const int tid = threadIdx.x;
  const int n = blockIdx.y;
  const int p0 = blockIdx.x * 64;

  for (int e = tid; e < 40*64; e += 256) {
    int ci = e >> 6, t = e & 63;
    xs[ci][t] = x[((size_t)n*40 + ci)*L0 + p0 + t];
  }
  for (int e = tid; e < 128*40; e += 256)
    wl[(e/40)*41 + (e%40)] = w[e];
  __syncthreads();

  const int c  = tid & 127;
  const int ph = tid >> 7;
  const float bias = b[c];
  #pragma unroll 4
  for (int k = 0; k < 32; ++k) {
    int p = ph + 2*k;
    float acc = bias;
    #pragma unroll
    for (int ci = 0; ci < 40; ++ci)
      acc = fmaf(wl[c*41 + ci], xs[ci][p], acc);
    H[((size_t)n*L0 + p0 + p)*128 + c] = f2bf(acc);
  }
}

__global__ __launch_bounds__(256) void layer_mfma(
    const unsigned short* __restrict__ Hin, unsigned short* __restrict__ Hout,
    float* __restrict__ SK,
    const unsigned short* __restrict__ Wd, const float* __restrict__ db,
    const unsigned short* __restrict__ Wr, const float* __restrict__ rb,
    const unsigned short* __restrict__ Ws, const float* __restrict__ sb,
    int d, int Lout, int accum)
{
  __shared__ unsigned short taps[64*256];

  const int tid = threadIdx.x;
  const int lb = blockIdx.x + gridDim.x * blockIdx.y;
  const int n  = lb & 7;
  const int bx = lb >> 3;
  const int p0 = (L0 - Lout) + bx * 64;
  const unsigned short* __restrict__ Hn = Hin + (size_t)n * L0 * 128;

  const int w  = tid >> 6, lane = tid & 63;
  const int ln = lane & 31, hi = lane >> 5;

  #pragma unroll
  for (int it = 0; it < 8; ++it) {
    int e = it * 256 + tid;
    int c8  = (e & 15) << 3;
    int p   = (e >> 4) & 63;
    int tap = e >> 10;
    int gp = p0 + p - (tap ? 0 : d);
    if (gp > L0 - 1) gp = L0 - 1;
    short8 v = *(const short8*)&Hn[(size_t)gp * 128 + c8];
    int byte = ((p << 9) + (((tap << 7) + c8) << 1)) ^ ((p & 7) << 4);
    *(short8*)((char*)taps + byte) = v;
  }
  __syncthreads();

  const f32x16 fz16 = {0.f};
  f32x16 af[2] = {fz16, fz16}, ag[2] = {fz16, fz16};
  #pragma unroll
  for (int ks = 0; ks < 16; ++ks) {
    int kb = ks*32 + hi*16;
    int pA = ln, pB = 32 + ln;
    short8 B0 = *(const short8*)((const char*)taps + (((pA << 9) + kb) ^ ((pA & 7) << 4)));
    short8 B1 = *(const short8*)((const char*)taps + (((pB << 9) + kb) ^ ((pB & 7) << 4)));
    short8 Af = *(const short8*)&Wd[(size_t)(32*w + ln) * 256 + ks*16 + hi*8];
    short8 Ag = *(const short8*)&Wd[(size_t)(128 + 32*w + ln) * 256 + ks*16 + hi*8];
    af[0] = __builtin_amdgcn_mfma_f32_32x32x16_bf16(Af, B0, af[0], 0, 0, 0);
    af[1] = __builtin_amdgcn_mfma_f32_32x32x16_bf16(Af, B1, af[1], 0, 0, 0);
    ag[0] = __builtin_amdgcn_mfma_f32_32x32x16_bf16(Ag, B0, ag[0], 0, 0, 0);
    ag[1] = __builtin_amdgcn_mfma_f32_32x32x16_bf16(Ag, B1, ag[1], 0, 0, 0);
  }

  __syncthreads();
  #pragma unroll
  for (int nb = 0; nb < 2; ++nb) {
    int p = nb*32 + ln;
    #pragma unroll
    for (int q = 0; q < 4; ++q) {
      int rbase = 8*q + 4*hi;
      const float4 bf4 = *(const float4*)&db[32*w + rbase];
      const float4 bg4 = *(const float4*)&db[128 + 32*w + rbase];
      const float bfv[4] = {bf4.x, bf4.y, bf4.z, bf4.w};
      const float bgv[4] = {bg4.x, bg4.y, bg4.z, bg4.w};
      unsigned short gs[4];
      #pragma unroll
      for (int r = 0; r < 4; ++r) {
        float fv = af[nb][4*q + r] + bfv[r];
        float gg = ag[nb][4*q + r] + bgv[r];
        float th = 2.f * __builtin_amdgcn_rcpf(1.f + __expf(-2.f * fv)) - 1.f;
        float sg = __builtin_amdgcn_rcpf(1.f + __expf(-gg));
        gs[r] = f2bf(th * sg);
      }
      ushort4 gv; gv.x = gs[0]; gv.y = gs[1]; gv.z = gs[2]; gv.w = gs[3];
      int byte = ((p << 9) + ((32*w + rbase) << 1)) ^ ((p & 7) << 4);
      *(ushort4*)((char*)taps + byte) = gv;
    }
  }
  __syncthreads();

  short8 Bg[2][8];
  #pragma unroll
  for (int nb = 0; nb < 2; ++nb) {
    int p = nb*32 + ln;
    #pragma unroll
    for (int ks = 0; ks < 8; ++ks)
      Bg[nb][ks] = *(const short8*)((const char*)taps +
                     (((p << 9) + ks*32 + hi*16) ^ ((p & 7) << 4)));
  }

  float* SKn = SK + (size_t)n * LFIN * 256;
  unsigned short* Hon = Hout + (size_t)n * L0 * 128;

  if (p0 + 63 >= PSKIP) {
    #pragma unroll
    for (int t = 0; t < 2; ++t) {
      const unsigned short* Aw = Ws + (size_t)(32*w + 128*t) * 128;
      f32x16 acc[2] = {fz16, fz16};
      #pragma unroll
      for (int ks = 0; ks < 8; ++ks) {
        short8 A = *(const short8*)&Aw[(size_t)ln * 128 + ks*16 + hi*8];
        acc[0] = __builtin_amdgcn_mfma_f32_32x32x16_bf16(A, Bg[0][ks], acc[0], 0, 0, 0);
        acc[1] = __builtin_amdgcn_mfma_f32_32x32x16_bf16(A, Bg[1][ks], acc[1], 0, 0, 0);
      }
      #pragma unroll
      for (int nb = 0; nb < 2; ++nb) {
        int p = p0 + nb*32 + ln;
        if (p >= PSKIP && p < L0) {
          #pragma unroll
          for (int q = 0; q < 4; ++q) {
            int co = 32*w + 128*t + 8*q + 4*hi;
            const float4 sb4 = *(const float4*)&sb[co];
            float* dst = &SKn[(size_t)(p - PSKIP) * 256 + co];
            float4 v = make_float4(acc[nb][4*q]   + sb4.x, acc[nb][4*q+1] + sb4.y,
                                   acc[nb][4*q+2] + sb4.z, acc[nb][4*q+3] + sb4.w);
            if (accum) {
              float4 o = *(const float4*)dst;
              v.x += o.x; v.y += o.y; v.z += o.z; v.w += o.w;
            }
            *(float4*)dst = v;
          }
        }
      }
    }
  }
  {
    const unsigned short* Aw = Wr + (size_t)(32*w) * 128;
    f32x16 acc[2] = {fz16, fz16};
    #pragma unroll
    for (int ks = 0; ks < 8; ++ks) {
      short8 A = *(const short8*)&Aw[(size_t)ln * 128 + ks*16 + hi*8];
      acc[0] = __builtin_amdgcn_mfma_f32_32x32x16_bf16(A, Bg[0][ks], acc[0], 0, 0, 0);
      acc[1] = __builtin_amdgcn_mfma_f32_32x32x16_bf16(A, Bg[1][ks], acc[1], 0, 0, 0);
    }
    #pragma unroll
    for (int nb = 0; nb < 2; ++nb) {
      int pl = nb*32 + ln;
      int p = p0 + pl;
      if (p < L0) {
        #pragma unroll
        for (int q = 0; q < 4; ++q) {
          int co = 32*w + 8*q + 4*hi;
          const float4 rb4 = *(const float4*)&rb[co];
          ushort4 hv = *(const ushort4*)((const char*)taps +
                         (((pl << 9) + ((128 + co) << 1)) ^ ((pl & 7) << 4)));
          ushort4 hb;
          hb.x = f2bf(acc[nb][4*q]   + rb4.x + bf2f(hv.x));
          hb.y = f2bf(acc[nb][4*q+1] + rb4.y + bf2f(hv.y));
          hb.z = f2bf(acc[nb][4*q+2] + rb4.z + bf2f(hv.z));
          hb.w = f2bf(acc[nb][4*q+3] + rb4.w + bf2f(hv.w));
          *(ushort4*)&Hon[(size_t)p * 128 + co] = hb;
        }
      }
    }
  }
}

__global__ __launch_bounds__(256) void end_mfma(
    const float* __restrict__ SK, const unsigned short* __restrict__ We,
    const float* __restrict__ eb, float* __restrict__ out)
{
  __shared__ unsigned short sl[64*256];
  const int tid = threadIdx.x;
  const int n = blockIdx.y;
  const int p0 = blockIdx.x * 64;
  const float* __restrict__ SKn = SK + (size_t)n * LFIN * 256;

  #pragma unroll
  for (int it = 0; it < 16; ++it) {
    int e = it * 256 + tid;
    int c4 = (e & 63) << 2;
    int p  = e >> 6;
    int gp = p0 + p; if (gp > LFIN - 1) gp = LFIN - 1;
    float4 v = *(const float4*)&SKn[(size_t)gp * 256 + c4];
    ushort4 h;
    h.x = f2bf(fmaxf(v.x, 0.f)); h.y = f2bf(fmaxf(v.y, 0.f));
    h.z = f2bf(fmaxf(v.z, 0.f)); h.w = f2bf(fmaxf(v.w, 0.f));
    int byte = ((p << 9) + (c4 << 1)) ^ ((p & 7) << 4);
    *(ushort4*)((char*)sl + byte) = h;
  }
  __syncthreads();

  const int w  = tid >> 6, lane = tid & 63;
  const int lr = lane & 15, lg = lane >> 4;
  const f32x4 fz = {0.f, 0.f, 0.f, 0.f};
  f32x4 acc[4] = {fz, fz, fz, fz};

  #pragma unroll
  for (int ks = 0; ks < 8; ++ks) {
    short8 A = *(const short8*)&We[(size_t)(16*w + lr) * 256 + ks*32 + lg*8];
    #pragma unroll
    for (int nb = 0; nb < 4; ++nb) {
      int p = nb * 16 + lr;
      int byte = ((p << 9) + ((ks*32 + lg*8) << 1)) ^ ((p & 7) << 4);
      short8 B = *(const short8*)((const char*)sl + byte);
      acc[nb] = __builtin_amdgcn_mfma_f32_16x16x32_bf16(A, B, acc[nb], 0, 0, 0);
    }
  }
  #pragma unroll
  for (int nb = 0; nb < 4; ++nb) {
    int p = p0 + nb*16 + lr;
    if (p < LFIN) {
      #pragma unroll
      for (int r = 0; r < 4; ++r) {
        int co = 16*w + lg*4 + r;
        out[((size_t)n*64 + co) * LFIN + p] = acc[nb][r] + eb[co];
      }
    }
  }
}

// ---------------- host ----------------
extern "C" void kernel_launch(void* const* d_in, const int* in_sizes, int n_in,
                              void* d_out, int out_size, void* d_ws, size_t ws_size,
                              hipStream_t stream)
{
  const float* x      = (const float*)d_in[0];
  const float* startw = (const float*)d_in[1];
  const float* startb = (const float*)d_in[2];
  const float* dilw   = (const float*)d_in[3];
  const float* dilb   = (const float*)d_in[4];
  const float* resw   = (const float*)d_in[5];
  const float* resb   = (const float*)d_in[6];
  const float* skipw  = (const float*)d_in[7];
  const float* skipb  = (const float*)d_in[8];
  const float* endw   = (const float*)d_in[9];
  const float* endb   = (const float*)d_in[10];

  unsigned short* H0 = (unsigned short*)d_ws;       // [8][8192][128] bf16 pos-major
  unsigned short* H1 = H0 + (size_t)8*L0*128;
  float* SK = (float*)(H1 + (size_t)8*L0*128);      // fallback only: [8][4612][256] f32
  unsigned short* Wd = (unsigned short*)(SK + (size_t)8*LFIN*256);
  unsigned short* Wr = Wd + (size_t)39*65536;
  unsigned short* Ws = Wr + (size_t)39*16384;
  unsigned short* We = Ws + (size_t)39*32768;
  unsigned* bar = (unsigned*)(We + 16384);

  const int total = 39*65536 + 39*16384 + 39*32768 + 16384;
  wconv_kernel<<<(total + 255)/256, 256, 0, stream>>>(dilw, resw, skipw, endw, Wd, Wr, Ws, We);
  hipMemsetAsync(bar, 0, 8*sizeof(unsigned), stream);

  float* outp = (float*)d_out;
  void* args[] = {
    (void*)&x, (void*)&startw, (void*)&startb,
    (void*)&Wd, (void*)&dilb, (void*)&Wr, (void*)&resb,
    (void*)&Ws, (void*)&skipb, (void*)&We, (void*)&endb,
    (void*)&H0, (void*)&H1, (void*)&outp, (void*)&bar };

  hipError_t ce = hipLaunchCooperativeKernel((void*)wavenet_all,
                                             dim3(1024), dim3(256), args, 0, stream);
  if (ce != hipSuccess) {
    // ---- fallback: proven round-3 multi-kernel path ----
    start_kernel<<<dim3(L0/64, 8), 256, 0, stream>>>(x, startw, startb, H0);
    unsigned short* bufs[2] = {H0, H1};
    int cur = 0, L = L0;
    for (int i = 0; i < 39; ++i) {
      int d = DILS[i];
      int Lout = L - d;
      dim3 grid((Lout + 63) / 64, 8);
      layer_mfma<<<grid, 256, 0, stream>>>(bufs[cur], bufs[cur ^ 1], SK,
          Wd + (size_t)i*65536, dilb + (size_t)i*256,
          Wr + (size_t)i*16384, resb + (size_t)i*128,
          Ws + (size_t)i*32768, skipb + (size_t)i*256,
          d, Lout, i ? 1 : 0);
      cur ^= 1;
      L = Lout;
    }
    end_mfma<<<dim3((LFIN + 63)/64, 8), 256, 0, stream>>>(SK, We, endb, outp);
  }
}

// Round 7
// 4415.982 us; speedup vs baseline: 1.7083x; 1.7083x over previous
//
#include <hip/hip_runtime.h>

typedef __attribute__((ext_vector_type(8)))  short short8;
typedef __attribute__((ext_vector_type(4)))  float f32x4;
typedef __attribute__((ext_vector_type(16))) float f32x16;

#define L0    8192
#define LFIN  4612
#define PSKIP 3580   // L0 - LFIN

__device__ __forceinline__ unsigned short f2bf(float f) {
  unsigned u = __builtin_bit_cast(unsigned, f);
  u += 0x7fffu + ((u >> 16) & 1u);          // RNE
  return (unsigned short)(u >> 16);
}
__device__ __forceinline__ float bf2f(unsigned short h) {
  return __builtin_bit_cast(float, (unsigned)h << 16);
}

// ---------------- weight conversion f32 -> bf16 + skip-bias total (once per call) ----
// Wd layout: [layer][co 256][k 256], k = tap*128 + ci  (tap0 @ p-d, tap1 @ p)
__global__ __launch_bounds__(256) void wconv_kernel(
    const float* __restrict__ dw, const float* __restrict__ rw,
    const float* __restrict__ sw, const float* __restrict__ ew,
    const float* __restrict__ skb,
    unsigned short* __restrict__ Wd, unsigned short* __restrict__ Wr,
    unsigned short* __restrict__ Ws, unsigned short* __restrict__ We,
    float* __restrict__ SBS)
{
  int e = blockIdx.x * 256 + threadIdx.x;
  const int ND = 39*65536, NR = 39*16384, NS = 39*32768, NE = 16384;
  if (e < ND) {
    int i = e >> 16, r = e & 65535;
    int co = r >> 8, k = r & 255;
    int tap = k >> 7, ci = k & 127;
    Wd[e] = f2bf(dw[(((size_t)i*256 + co)*128 + ci)*2 + tap]);
  } else if ((e -= ND) < NR) {
    Wr[e] = f2bf(rw[e]);
  } else if ((e -= NR) < NS) {
    Ws[e] = f2bf(sw[e]);
  } else if ((e -= NS) < NE) {
    We[e] = f2bf(ew[e]);
  } else if ((e -= NE) < 256) {
    float s = 0.f;
    for (int i = 0; i < 39; ++i) s += skb[i*256 + e];
    SBS[e] = s;
  }
}

// ---------------- start: 1x1 conv 40 -> 128, position-major bf16 output ----------------
__global__ __launch_bounds__(256) void start_kernel(
    const float* __restrict__ x, const float* __restrict__ w,
    const float* __restrict__ b, unsigned short* __restrict__ H)
{
  __shared__ float xs[40][64];
  __shared__ float wl[128*41];
  const int tid = threadIdx.x;
  const int n = blockIdx.y;
  const int p0 = blockIdx.x * 64;

  for (int e = tid; e < 40*64; e += 256) {
    int ci = e >> 6, t = e & 63;
    xs[ci][t] = x[((size_t)n*40 + ci)*L0 + p0 + t];
  }
  for (int e = tid; e < 128*40; e += 256)
    wl[(e/40)*41 + (e%40)] = w[e];
  __syncthreads();

  const int c  = tid & 127;
  const int ph = tid >> 7;                 // 0..1
  const float bias = b[c];
  #pragma unroll 4
  for (int k = 0; k < 32; ++k) {
    int p = ph + 2*k;
    float acc = bias;
    #pragma unroll
    for (int ci = 0; ci < 40; ++ci)
      acc = fmaf(wl[c*41 + ci], xs[ci][p], acc);
    H[((size_t)n*L0 + p0 + p)*128 + c] = f2bf(acc);
  }
}

// ---------------- gate f/g -> bf16 into Gl row p ----------------
__device__ __forceinline__ void gate_write(char* Gl, const float* __restrict__ dbl,
    const f32x16& af, const f32x16& ag, int p, int w, int hi)
{
  #pragma unroll
  for (int q = 0; q < 4; ++q) {
    int rbase = 8*q + 4*hi;
    const float4 bf4 = *(const float4*)&dbl[32*w + rbase];
    const float4 bg4 = *(const float4*)&dbl[128 + 32*w + rbase];
    const float bfv[4] = {bf4.x, bf4.y, bf4.z, bf4.w};
    const float bgv[4] = {bg4.x, bg4.y, bg4.z, bg4.w};
    unsigned short gs[4];
    #pragma unroll
    for (int r = 0; r < 4; ++r) {
      float fv = af[4*q + r] + bfv[r];
      float gg = ag[4*q + r] + bgv[r];
      float th = 2.f * __builtin_amdgcn_rcpf(1.f + __expf(-2.f * fv)) - 1.f;
      float sg = __builtin_amdgcn_rcpf(1.f + __expf(-gg));
      gs[r] = f2bf(th * sg);
    }
    ushort4 gv; gv.x = gs[0]; gv.y = gs[1]; gv.z = gs[2]; gv.w = gs[3];
    int byte = ((p << 8) + ((32*w + rbase) << 1)) ^ ((p & 7) << 4);
    *(ushort4*)(Gl + byte) = gv;
  }
}

// ---------------- fused group of NL dilated layers (dils = s*{1,2,4,8,16}) ----------
// Block owns 64 output positions strided by s, +32-slot strided halo: 96 slots in LDS.
// All inter-layer deps stay in the block (mod-s residue chains) -> NO global sync.
// H chain bitwise identical to per-layer kernels (same bf16 rounding points).
// Skip outputs accumulate in persistent registers sk[2][2]; one SK RMW per group.
__global__ __launch_bounds__(256, 2) void group_mfma(
    const unsigned short* __restrict__ Hin, unsigned short* __restrict__ Hout,
    float* __restrict__ SK,
    const unsigned short* __restrict__ Wd, const float* __restrict__ dilb,
    const unsigned short* __restrict__ Wr, const float* __restrict__ resb,
    const unsigned short* __restrict__ Ws,
    int s, int NL, int i0, int accum, int writeH)
{
  __shared__ __align__(16) unsigned short Hl[96*128];   // 24 KiB, row 256B swizzled
  __shared__ __align__(16) unsigned short Gl[96*128];   // 24 KiB

  const int tid = threadIdx.x;
  const int lb = blockIdx.x;
  const int n = lb & 7;                 // batch
  const int u = lb >> 3;                // 0..127
  const int r = (s == 1) ? 0 : (u & 31);
  const int t = (s == 1) ? u : (u >> 5);
  const int mbase = t*64 - 32;          // slot j -> m = mbase + j ; pos = r + s*m

  const int w = tid >> 6, lane = tid & 63;
  const int ln = lane & 31, hi = lane >> 5;

  const unsigned short* __restrict__ Hb = Hin + (size_t)n * L0 * 128;

  // ---- stage 96 slots from global H ----
  #pragma unroll
  for (int it = 0; it < 6; ++it) {
    int e = it*256 + tid;               // 96 rows x 16 threads
    int c8 = (e & 15) << 3;
    int j  = e >> 4;
    int gp = r + s * (mbase + j);
    if (gp < 0) gp = 0;                 // halo below valid region: bounded garbage, unused
    short8 v = *(const short8*)&Hb[(size_t)gp * 128 + c8];
    *(short8*)((char*)Hl + (((j << 8) + (c8 << 1)) ^ ((j & 7) << 4))) = v;
  }
  __syncthreads();

  const f32x16 fz16 = {0.f};
  f32x16 sk[2][2] = {{fz16, fz16}, {fz16, fz16}};
  const bool doSkip = (r + s*(t*64 + 63)) >= PSKIP;

  for (int l = 0; l < NL; ++l) {
    const int i = i0 + l;
    const int dil = 1 << l;             // dilation in slot space
    const unsigned short* __restrict__ Wdl = Wd + (size_t)l*65536;

    // ---- GEMM1: 3 slot-tiles, weights hoisted (Wd read once per sub-layer) ----
    f32x16 af[3] = {fz16, fz16, fz16}, ag[3] = {fz16, fz16, fz16};
    int rc0[3], row1[3];
    #pragma unroll
    for (int nb = 0; nb < 3; ++nb) {
      row1[nb] = nb*32 + ln;
      int rr = row1[nb] - dil; if (rr < 0) rr = 0;
      rc0[nb] = rr;
    }
    #pragma unroll
    for (int ks = 0; ks < 16; ++ks) {
      int colb = (ks & 7)*32 + hi*16;
      short8 Af = *(const short8*)&Wdl[(size_t)(32*w + ln)*256 + ks*16 + hi*8];
      short8 Ag = *(const short8*)&Wdl[(size_t)(128 + 32*w + ln)*256 + ks*16 + hi*8];
      #pragma unroll
      for (int nb = 0; nb < 3; ++nb) {
        int row = (ks < 8) ? rc0[nb] : row1[nb];
        short8 B = *(const short8*)((const char*)Hl +
                     ((row << 8) + (colb ^ ((row & 7) << 4))));
        af[nb] = __builtin_amdgcn_mfma_f32_32x32x16_bf16(Af, B, af[nb], 0, 0, 0);
        ag[nb] = __builtin_amdgcn_mfma_f32_32x32x16_bf16(Ag, B, ag[nb], 0, 0, 0);
      }
    }

    // ---- gate into Gl ----
    const float* dbl = dilb + l*256;
    #pragma unroll
    for (int nb = 0; nb < 3; ++nb)
      gate_write((char*)Gl, dbl, af[nb], ag[nb], nb*32 + ln, w, hi);
    __syncthreads();                    // Gl complete; all Hl reads of GEMM1 done

    // ---- skip GEMM on own tiles (slots 32..95) -> persistent sk ----
    if (doSkip) {
      const unsigned short* __restrict__ Wsl = Ws + (size_t)l*32768;
      #pragma unroll
      for (int ks = 0; ks < 8; ++ks) {
        int colb = ks*32 + hi*16;
        short8 A0 = *(const short8*)&Wsl[(size_t)(32*w + ln)*128 + ks*16 + hi*8];
        short8 A1 = *(const short8*)&Wsl[(size_t)(128 + 32*w + ln)*128 + ks*16 + hi*8];
        #pragma unroll
        for (int nb = 0; nb < 2; ++nb) {
          int row = 32 + nb*32 + ln;
          short8 B = *(const short8*)((const char*)Gl +
                       ((row << 8) + (colb ^ ((row & 7) << 4))));
          sk[0][nb] = __builtin_amdgcn_mfma_f32_32x32x16_bf16(A0, B, sk[0][nb], 0, 0, 0);
          sk[1][nb] = __builtin_amdgcn_mfma_f32_32x32x16_bf16(A1, B, sk[1][nb], 0, 0, 0);
        }
      }
    }

    // ---- res GEMM + residual: update Hl in place ----
    if (i < 38) {
      const unsigned short* __restrict__ Wrl = Wr + (size_t)l*16384;
      const float* rbl = resb + l*128;
      const int nbLo = (l == NL-1) ? 1 : 0;      // last sub-layer: own tiles only
      f32x16 racc[3] = {fz16, fz16, fz16};
      #pragma unroll
      for (int ks = 0; ks < 8; ++ks) {
        int colb = ks*32 + hi*16;
        short8 A = *(const short8*)&Wrl[(size_t)(32*w + ln)*128 + ks*16 + hi*8];
        for (int nb = nbLo; nb < 3; ++nb) {
          int row = nb*32 + ln;
          short8 B = *(const short8*)((const char*)Gl +
                       ((row << 8) + (colb ^ ((row & 7) << 4))));
          racc[nb] = __builtin_amdgcn_mfma_f32_32x32x16_bf16(A, B, racc[nb], 0, 0, 0);
        }
      }
      for (int nb = nbLo; nb < 3; ++nb) {
        int sl = nb*32 + ln;
        #pragma unroll
        for (int q = 0; q < 4; ++q) {
          int co = 32*w + 8*q + 4*hi;
          const float4 rb4 = *(const float4*)&rbl[co];
          int hbyte = ((sl << 8) + (co << 1)) ^ ((sl & 7) << 4);
          ushort4 hv = *(const ushort4*)((const char*)Hl + hbyte);
          ushort4 hb;
          hb.x = f2bf(racc[nb][4*q]   + rb4.x + bf2f(hv.x));
          hb.y = f2bf(racc[nb][4*q+1] + rb4.y + bf2f(hv.y));
          hb.z = f2bf(racc[nb][4*q+2] + rb4.z + bf2f(hv.z));
          hb.w = f2bf(racc[nb][4*q+3] + rb4.w + bf2f(hv.w));
          *(ushort4*)((char*)Hl + hbyte) = hb;
        }
      }
    }
    __syncthreads();                    // Hl ready for next sub-layer; Gl reads done
  }

  // ---- write own 64 slots of final H to global (not needed after last group) ----
  if (writeH) {
    unsigned short* __restrict__ Ho = Hout + (size_t)n * L0 * 128;
    #pragma unroll
    for (int it = 0; it < 4; ++it) {
      int e = it*256 + tid;             // 64 rows x 16 threads
      int c8 = (e & 15) << 3;
      int j  = 32 + (e >> 4);
      int gp = r + s * (mbase + j);     // in [0, 8191] for own slots
      short8 v = *(const short8*)((const char*)Hl +
                   (((j << 8) + (c8 << 1)) ^ ((j & 7) << 4)));
      *(short8*)&Ho[(size_t)gp * 128 + c8] = v;
    }
  }

  // ---- SK read-modify-write, once per group ----
  if (doSkip) {
    float* SKn = SK + (size_t)n * LFIN * 256;
    #pragma unroll
    for (int tt = 0; tt < 2; ++tt) {
      #pragma unroll
      for (int nb = 0; nb < 2; ++nb) {
        int sl = 32 + nb*32 + ln;
        int p = r + s * (mbase + sl);
        if (p >= PSKIP) {
          int pi = p - PSKIP;
          #pragma unroll
          for (int q = 0; q < 4; ++q) {
            int co = 32*w + 128*tt + 8*q + 4*hi;
            float* dst = &SKn[(size_t)pi * 256 + co];
            float4 v = make_float4(sk[tt][nb][4*q],   sk[tt][nb][4*q+1],
                                   sk[tt][nb][4*q+2], sk[tt][nb][4*q+3]);
            if (accum) {
              float4 o = *(const float4*)dst;
              v.x += o.x; v.y += o.y; v.z += o.z; v.w += o.w;
            }
            *(float4*)dst = v;
          }
        }
      }
    }
  }
}

// ---------------- end: relu(skip + total skip-bias) + 1x1 conv 256 -> 64 ----------------
__global__ __launch_bounds__(256) void end_mfma(
    const float* __restrict__ SK, const unsigned short* __restrict__ We,
    const float* __restrict__ SBS, const float* __restrict__ eb,
    float* __restrict__ out)
{
  __shared__ unsigned short sl[64*256];
  const int tid = threadIdx.x;
  const int n = blockIdx.y;
  const int p0 = blockIdx.x * 64;
  const float* __restrict__ SKn = SK + (size_t)n * LFIN * 256;

  #pragma unroll
  for (int it = 0; it < 16; ++it) {
    int e = it * 256 + tid;
    int c4 = (e & 63) << 2;
    int p  = e >> 6;
    int gp = p0 + p; if (gp > LFIN - 1) gp = LFIN - 1;
    float4 v = *(const float4*)&SKn[(size_t)gp * 256 + c4];
    float4 s4 = *(const float4*)&SBS[c4];
    ushort4 h;
    h.x = f2bf(fmaxf(v.x + s4.x, 0.f)); h.y = f2bf(fmaxf(v.y + s4.y, 0.f));
    h.z = f2bf(fmaxf(v.z + s4.z, 0.f)); h.w = f2bf(fmaxf(v.w + s4.w, 0.f));
    int byte = ((p << 9) + (c4 << 1)) ^ ((p & 7) << 4);
    *(ushort4*)((char*)sl + byte) = h;
  }
  __syncthreads();

  const int w  = tid >> 6, lane = tid & 63;
  const int lr = lane & 15, lg = lane >> 4;
  const f32x4 fz = {0.f, 0.f, 0.f, 0.f};
  f32x4 acc[4] = {fz, fz, fz, fz};

  #pragma unroll
  for (int ks = 0; ks < 8; ++ks) {
    short8 A = *(const short8*)&We[(size_t)(16*w + lr) * 256 + ks*32 + lg*8];
    #pragma unroll
    for (int nb = 0; nb < 4; ++nb) {
      int p = nb * 16 + lr;
      int byte = ((p << 9) + ((ks*32 + lg*8) << 1)) ^ ((p & 7) << 4);
      short8 B = *(const short8*)((const char*)sl + byte);
      acc[nb] = __builtin_amdgcn_mfma_f32_16x16x32_bf16(A, B, acc[nb], 0, 0, 0);
    }
  }
  #pragma unroll
  for (int nb = 0; nb < 4; ++nb) {
    int p = p0 + nb*16 + lr;
    if (p < LFIN) {
      #pragma unroll
      for (int r = 0; r < 4; ++r) {
        int co = 16*w + lg*4 + r;
        out[((size_t)n*64 + co) * LFIN + p] = acc[nb][r] + eb[co];
      }
    }
  }
}

// ---------------- host ----------------
extern "C" void kernel_launch(void* const* d_in, const int* in_sizes, int n_in,
                              void* d_out, int out_size, void* d_ws, size_t ws_size,
                              hipStream_t stream)
{
  const float* x      = (const float*)d_in[0];
  const float* startw = (const float*)d_in[1];
  const float* startb = (const float*)d_in[2];
  const float* dilw   = (const float*)d_in[3];
  const float* dilb   = (const float*)d_in[4];
  const float* resw   = (const float*)d_in[5];
  const float* resb   = (const float*)d_in[6];
  const float* skipw  = (const float*)d_in[7];
  const float* skipb  = (const float*)d_in[8];
  const float* endw   = (const float*)d_in[9];
  const float* endb   = (const float*)d_in[10];

  unsigned short* H0 = (unsigned short*)d_ws;       // [8][8192][128] bf16 pos-major
  unsigned short* H1 = H0 + (size_t)8*L0*128;
  float* SK = (float*)(H1 + (size_t)8*L0*128);      // [8][4612][256] f32 pos-major
  unsigned short* Wd = (unsigned short*)(SK + (size_t)8*LFIN*256);
  unsigned short* Wr = Wd + (size_t)39*65536;
  unsigned short* Ws = Wr + (size_t)39*16384;
  unsigned short* We = Ws + (size_t)39*32768;
  float* SBS = (float*)(We + 16384);

  const int total = 39*65536 + 39*16384 + 39*32768 + 16384 + 256;
  wconv_kernel<<<(total + 255)/256, 256, 0, stream>>>(dilw, resw, skipw, endw, skipb,
                                                      Wd, Wr, Ws, We, SBS);
  start_kernel<<<dim3(L0/64, 8), 256, 0, stream>>>(x, startw, startb, H0);

  // groups: 5 layers with dils s*{1,2,4,8,16} (last group: 4 layers)
  static const int GI0[8] = {0, 5, 10, 15, 20, 25, 30, 35};
  static const int GNL[8] = {5, 5, 5, 5, 5, 5, 5, 4};
  static const int GS [8] = {1, 32, 1, 32, 1, 32, 1, 32};

  unsigned short* bufs[2] = {H0, H1};
  for (int g = 0; g < 8; ++g) {
    int i0 = GI0[g];
    group_mfma<<<dim3(1024), 256, 0, stream>>>(
        bufs[g & 1], bufs[(g & 1) ^ 1], SK,
        Wd + (size_t)i0*65536, dilb + (size_t)i0*256,
        Wr + (size_t)i0*16384, resb + (size_t)i0*128,
        Ws + (size_t)i0*32768,
        GS[g], GNL[g], i0, g ? 1 : 0, (g < 7) ? 1 : 0);
  }

  end_mfma<<<dim3((LFIN + 63)/64, 8), 256, 0, stream>>>(SK, We, SBS, endb, (float*)d_out);
}

// Round 8
// 2065.081 us; speedup vs baseline: 3.6530x; 2.1384x over previous
//
#include <hip/hip_runtime.h>

typedef __attribute__((ext_vector_type(8)))  short short8;
typedef __attribute__((ext_vector_type(4)))  float f32x4;
typedef __attribute__((ext_vector_type(16))) float f32x16;

#define L0    8192
#define LFIN  4612
#define PSKIP 3580   // L0 - LFIN

__device__ __forceinline__ unsigned short f2bf(float f) {
  unsigned u = __builtin_bit_cast(unsigned, f);
  u += 0x7fffu + ((u >> 16) & 1u);          // RNE
  return (unsigned short)(u >> 16);
}
__device__ __forceinline__ float bf2f(unsigned short h) {
  return __builtin_bit_cast(float, (unsigned)h << 16);
}

// ---------------- weight conversion f32 -> bf16 + skip-bias total (once per call) ----
// Wd layout: [layer][co 256][k 256], k = tap*128 + ci  (tap0 @ p-d, tap1 @ p)
__global__ __launch_bounds__(256) void wconv_kernel(
    const float* __restrict__ dw, const float* __restrict__ rw,
    const float* __restrict__ sw, const float* __restrict__ ew,
    const float* __restrict__ skb,
    unsigned short* __restrict__ Wd, unsigned short* __restrict__ Wr,
    unsigned short* __restrict__ Ws, unsigned short* __restrict__ We,
    float* __restrict__ SBS)
{
  int e = blockIdx.x * 256 + threadIdx.x;
  const int ND = 39*65536, NR = 39*16384, NS = 39*32768, NE = 16384;
  if (e < ND) {
    int i = e >> 16, r = e & 65535;
    int co = r >> 8, k = r & 255;
    int tap = k >> 7, ci = k & 127;
    Wd[e] = f2bf(dw[(((size_t)i*256 + co)*128 + ci)*2 + tap]);
  } else if ((e -= ND) < NR) {
    Wr[e] = f2bf(rw[e]);
  } else if ((e -= NR) < NS) {
    Ws[e] = f2bf(sw[e]);
  } else if ((e -= NS) < NE) {
    We[e] = f2bf(ew[e]);
  } else if ((e -= NE) < 256) {
    float s = 0.f;
    for (int i = 0; i < 39; ++i) s += skb[i*256 + e];
    SBS[e] = s;
  }
}

// ---------------- start: 1x1 conv 40 -> 128, position-major bf16 output ----------------
__global__ __launch_bounds__(256) void start_kernel(
    const float* __restrict__ x, const float* __restrict__ w,
    const float* __restrict__ b, unsigned short* __restrict__ H)
{
  __shared__ float xs[40][64];
  __shared__ float wl[128*41];
  const int tid = threadIdx.x;
  const int n = blockIdx.y;
  const int p0 = blockIdx.x * 64;

  for (int e = tid; e < 40*64; e += 256) {
    int ci = e >> 6, t = e & 63;
    xs[ci][t] = x[((size_t)n*40 + ci)*L0 + p0 + t];
  }
  for (int e = tid; e < 128*40; e += 256)
    wl[(e/40)*41 + (e%40)] = w[e];
  __syncthreads();

  const int c  = tid & 127;
  const int ph = tid >> 7;                 // 0..1
  const float bias = b[c];
  #pragma unroll 4
  for (int k = 0; k < 32; ++k) {
    int p = ph + 2*k;
    float acc = bias;
    #pragma unroll
    for (int ci = 0; ci < 40; ++ci)
      acc = fmaf(wl[c*41 + ci], xs[ci][p], acc);
    H[((size_t)n*L0 + p0 + p)*128 + c] = f2bf(acc);
  }
}

// ---------------- gate f/g -> bf16 into Gl row p ----------------
__device__ __forceinline__ void gate_write(char* Gl, const float* __restrict__ dbl,
    const f32x16& af, const f32x16& ag, int p, int w, int hi)
{
  #pragma unroll
  for (int q = 0; q < 4; ++q) {
    int rbase = 8*q + 4*hi;
    const float4 bf4 = *(const float4*)&dbl[32*w + rbase];
    const float4 bg4 = *(const float4*)&dbl[128 + 32*w + rbase];
    const float bfv[4] = {bf4.x, bf4.y, bf4.z, bf4.w};
    const float bgv[4] = {bg4.x, bg4.y, bg4.z, bg4.w};
    unsigned short gs[4];
    #pragma unroll
    for (int r = 0; r < 4; ++r) {
      float fv = af[4*q + r] + bfv[r];
      float gg = ag[4*q + r] + bgv[r];
      float th = 2.f * __builtin_amdgcn_rcpf(1.f + __expf(-2.f * fv)) - 1.f;
      float sg = __builtin_amdgcn_rcpf(1.f + __expf(-gg));
      gs[r] = f2bf(th * sg);
    }
    ushort4 gv; gv.x = gs[0]; gv.y = gs[1]; gv.z = gs[2]; gv.w = gs[3];
    int byte = ((p << 8) + ((32*w + rbase) << 1)) ^ ((p & 7) << 4);
    *(ushort4*)(Gl + byte) = gv;
  }
}

// ---------------- fused group of NL dilated layers (dils = s*{1,2,4,8,16}) ----------
// Block owns 64 output positions strided by s, +32-slot strided halo: 96 slots in LDS.
// All inter-layer deps stay in the block (mod-s residue chains) -> NO global sync.
// GEMM1/res split per 32-row tile to keep live VGPRs low (R7 spilled at 6 live f32x16
// accumulators under a 128-reg cap -> 1 GB/dispatch scratch traffic).
// Skip accumulators: four NAMED f32x16 regs, persistent across sub-layers.
__global__ __launch_bounds__(256, 1) void group_mfma(
    const unsigned short* __restrict__ Hin, unsigned short* __restrict__ Hout,
    float* __restrict__ SK,
    const unsigned short* __restrict__ Wd, const float* __restrict__ dilb,
    const unsigned short* __restrict__ Wr, const float* __restrict__ resb,
    const unsigned short* __restrict__ Ws,
    int s, int NL, int i0, int accum, int writeH)
{
  __shared__ __align__(16) unsigned short Hl[96*128];   // 24 KiB, row 256B swizzled
  __shared__ __align__(16) unsigned short Gl[96*128];   // 24 KiB

  const int tid = threadIdx.x;
  const int lb = blockIdx.x;
  const int n = lb & 7;                 // batch
  const int u = lb >> 3;                // 0..127
  const int r = (s == 1) ? 0 : (u & 31);
  const int t = (s == 1) ? u : (u >> 5);
  const int mbase = t*64 - 32;          // slot j -> m = mbase + j ; pos = r + s*m

  const int w = tid >> 6, lane = tid & 63;
  const int ln = lane & 31, hi = lane >> 5;

  const unsigned short* __restrict__ Hb = Hin + (size_t)n * L0 * 128;

  // ---- stage 96 slots from global H ----
  #pragma unroll
  for (int it = 0; it < 6; ++it) {
    int e = it*256 + tid;               // 96 rows x 16 threads
    int c8 = (e & 15) << 3;
    int j  = e >> 4;
    int gp = r + s * (mbase + j);
    if (gp < 0) gp = 0;                 // halo below valid region: bounded garbage, unused
    short8 v = *(const short8*)&Hb[(size_t)gp * 128 + c8];
    *(short8*)((char*)Hl + (((j << 8) + (c8 << 1)) ^ ((j & 7) << 4))) = v;
  }
  __syncthreads();

  const f32x16 fz16 = {0.f};
  f32x16 sk00 = fz16, sk01 = fz16, sk10 = fz16, sk11 = fz16;
  const bool doSkip = (r + s*(t*64 + 63)) >= PSKIP;

  #pragma unroll 1
  for (int l = 0; l < NL; ++l) {
    const int i = i0 + l;
    const int dil = 1 << l;             // dilation in slot space
    const unsigned short* __restrict__ Wdl = Wd + (size_t)l*65536;
    const float* dbl = dilb + l*256;

    // ---- GEMM1 + gate, one 32-row tile at a time (2 live f32x16) ----
    #pragma unroll 1
    for (int nb = 0; nb < 3; ++nb) {
      const int row1 = nb*32 + ln;
      int rc0 = row1 - dil; if (rc0 < 0) rc0 = 0;
      f32x16 af = fz16, ag = fz16;
      #pragma unroll
      for (int ks = 0; ks < 16; ++ks) {
        int colb = (ks & 7)*32 + hi*16;
        int row = (ks < 8) ? rc0 : row1;
        short8 B  = *(const short8*)((const char*)Hl +
                      ((row << 8) + (colb ^ ((row & 7) << 4))));
        short8 Af = *(const short8*)&Wdl[(size_t)(32*w + ln)*256 + ks*16 + hi*8];
        short8 Ag = *(const short8*)&Wdl[(size_t)(128 + 32*w + ln)*256 + ks*16 + hi*8];
        af = __builtin_amdgcn_mfma_f32_32x32x16_bf16(Af, B, af, 0, 0, 0);
        ag = __builtin_amdgcn_mfma_f32_32x32x16_bf16(Ag, B, ag, 0, 0, 0);
      }
      gate_write((char*)Gl, dbl, af, ag, row1, w, hi);
    }
    __syncthreads();                    // Gl complete; all Hl reads of GEMM1 done

    // ---- skip GEMM on own tiles (slots 32..95) -> persistent named sk regs ----
    if (doSkip) {
      const unsigned short* __restrict__ Wsl = Ws + (size_t)l*32768;
      const int rB0 = 32 + ln, rB1 = 64 + ln;
      #pragma unroll
      for (int ks = 0; ks < 8; ++ks) {
        int colb = ks*32 + hi*16;
        short8 A0 = *(const short8*)&Wsl[(size_t)(32*w + ln)*128 + ks*16 + hi*8];
        short8 A1 = *(const short8*)&Wsl[(size_t)(128 + 32*w + ln)*128 + ks*16 + hi*8];
        short8 B0 = *(const short8*)((const char*)Gl +
                      ((rB0 << 8) + (colb ^ ((rB0 & 7) << 4))));
        short8 B1 = *(const short8*)((const char*)Gl +
                      ((rB1 << 8) + (colb ^ ((rB1 & 7) << 4))));
        sk00 = __builtin_amdgcn_mfma_f32_32x32x16_bf16(A0, B0, sk00, 0, 0, 0);
        sk01 = __builtin_amdgcn_mfma_f32_32x32x16_bf16(A0, B1, sk01, 0, 0, 0);
        sk10 = __builtin_amdgcn_mfma_f32_32x32x16_bf16(A1, B0, sk10, 0, 0, 0);
        sk11 = __builtin_amdgcn_mfma_f32_32x32x16_bf16(A1, B1, sk11, 0, 0, 0);
      }
    }

    // ---- res GEMM + residual, one tile at a time: update Hl in place ----
    if (i < 38) {
      const unsigned short* __restrict__ Wrl = Wr + (size_t)l*16384;
      const float* rbl = resb + l*128;
      #pragma unroll 1
      for (int nb = 0; nb < 3; ++nb) {
        if (nb == 0 && l == NL-1) continue;      // last sub-layer: own tiles only
        const int sl = nb*32 + ln;
        f32x16 racc = fz16;
        #pragma unroll
        for (int ks = 0; ks < 8; ++ks) {
          int colb = ks*32 + hi*16;
          short8 A = *(const short8*)&Wrl[(size_t)(32*w + ln)*128 + ks*16 + hi*8];
          short8 B = *(const short8*)((const char*)Gl +
                       ((sl << 8) + (colb ^ ((sl & 7) << 4))));
          racc = __builtin_amdgcn_mfma_f32_32x32x16_bf16(A, B, racc, 0, 0, 0);
        }
        #pragma unroll
        for (int q = 0; q < 4; ++q) {
          int co = 32*w + 8*q + 4*hi;
          const float4 rb4 = *(const float4*)&rbl[co];
          int hbyte = ((sl << 8) + (co << 1)) ^ ((sl & 7) << 4);
          ushort4 hv = *(const ushort4*)((const char*)Hl + hbyte);
          ushort4 hb;
          hb.x = f2bf(racc[4*q]   + rb4.x + bf2f(hv.x));
          hb.y = f2bf(racc[4*q+1] + rb4.y + bf2f(hv.y));
          hb.z = f2bf(racc[4*q+2] + rb4.z + bf2f(hv.z));
          hb.w = f2bf(racc[4*q+3] + rb4.w + bf2f(hv.w));
          *(ushort4*)((char*)Hl + hbyte) = hb;
        }
      }
    }
    __syncthreads();                    // Hl ready for next sub-layer; Gl reads done
  }

  // ---- write own 64 slots of final H to global (not needed after last group) ----
  if (writeH) {
    unsigned short* __restrict__ Ho = Hout + (size_t)n * L0 * 128;
    #pragma unroll
    for (int it = 0; it < 4; ++it) {
      int e = it*256 + tid;             // 64 rows x 16 threads
      int c8 = (e & 15) << 3;
      int j  = 32 + (e >> 4);
      int gp = r + s * (mbase + j);     // in [0, 8191] for own slots
      short8 v = *(const short8*)((const char*)Hl +
                   (((j << 8) + (c8 << 1)) ^ ((j & 7) << 4)));
      *(short8*)&Ho[(size_t)gp * 128 + c8] = v;
    }
  }

  // ---- SK read-modify-write, once per group ----
  if (doSkip) {
    float* SKn = SK + (size_t)n * LFIN * 256;
    #pragma unroll
    for (int nb = 0; nb < 2; ++nb) {
      int sl = 32 + nb*32 + ln;
      int p = r + s * (mbase + sl);
      if (p >= PSKIP) {
        int pi = p - PSKIP;
        #pragma unroll
        for (int q = 0; q < 4; ++q) {
          const f32x16& a0 = nb ? sk01 : sk00;
          const f32x16& a1 = nb ? sk11 : sk10;
          {
            int co = 32*w + 8*q + 4*hi;
            float* dst = &SKn[(size_t)pi * 256 + co];
            float4 v = make_float4(a0[4*q], a0[4*q+1], a0[4*q+2], a0[4*q+3]);
            if (accum) {
              float4 o = *(const float4*)dst;
              v.x += o.x; v.y += o.y; v.z += o.z; v.w += o.w;
            }
            *(float4*)dst = v;
          }
          {
            int co = 32*w + 128 + 8*q + 4*hi;
            float* dst = &SKn[(size_t)pi * 256 + co];
            float4 v = make_float4(a1[4*q], a1[4*q+1], a1[4*q+2], a1[4*q+3]);
            if (accum) {
              float4 o = *(const float4*)dst;
              v.x += o.x; v.y += o.y; v.z += o.z; v.w += o.w;
            }
            *(float4*)dst = v;
          }
        }
      }
    }
  }
}

// ---------------- end: relu(skip + total skip-bias) + 1x1 conv 256 -> 64 ----------------
__global__ __launch_bounds__(256) void end_mfma(
    const float* __restrict__ SK, const unsigned short* __restrict__ We,
    const float* __restrict__ SBS, const float* __restrict__ eb,
    float* __restrict__ out)
{
  __shared__ unsigned short sl[64*256];
  const int tid = threadIdx.x;
  const int n = blockIdx.y;
  const int p0 = blockIdx.x * 64;
  const float* __restrict__ SKn = SK + (size_t)n * LFIN * 256;

  #pragma unroll
  for (int it = 0; it < 16; ++it) {
    int e = it * 256 + tid;
    int c4 = (e & 63) << 2;
    int p  = e >> 6;
    int gp = p0 + p; if (gp > LFIN - 1) gp = LFIN - 1;
    float4 v = *(const float4*)&SKn[(size_t)gp * 256 + c4];
    float4 s4 = *(const float4*)&SBS[c4];
    ushort4 h;
    h.x = f2bf(fmaxf(v.x + s4.x, 0.f)); h.y = f2bf(fmaxf(v.y + s4.y, 0.f));
    h.z = f2bf(fmaxf(v.z + s4.z, 0.f)); h.w = f2bf(fmaxf(v.w + s4.w, 0.f));
    int byte = ((p << 9) + (c4 << 1)) ^ ((p & 7) << 4);
    *(ushort4*)((char*)sl + byte) = h;
  }
  __syncthreads();

  const int w  = tid >> 6, lane = tid & 63;
  const int lr = lane & 15, lg = lane >> 4;
  const f32x4 fz = {0.f, 0.f, 0.f, 0.f};
  f32x4 acc[4] = {fz, fz, fz, fz};

  #pragma unroll
  for (int ks = 0; ks < 8; ++ks) {
    short8 A = *(const short8*)&We[(size_t)(16*w + lr) * 256 + ks*32 + lg*8];
    #pragma unroll
    for (int nb = 0; nb < 4; ++nb) {
      int p = nb * 16 + lr;
      int byte = ((p << 9) + ((ks*32 + lg*8) << 1)) ^ ((p & 7) << 4);
      short8 B = *(const short8*)((const char*)sl + byte);
      acc[nb] = __builtin_amdgcn_mfma_f32_16x16x32_bf16(A, B, acc[nb], 0, 0, 0);
    }
  }
  #pragma unroll
  for (int nb = 0; nb < 4; ++nb) {
    int p = p0 + nb*16 + lr;
    if (p < LFIN) {
      #pragma unroll
      for (int r = 0; r < 4; ++r) {
        int co = 16*w + lg*4 + r;
        out[((size_t)n*64 + co) * LFIN + p] = acc[nb][r] + eb[co];
      }
    }
  }
}

// ---------------- host ----------------
extern "C" void kernel_launch(void* const* d_in, const int* in_sizes, int n_in,
                              void* d_out, int out_size, void* d_ws, size_t ws_size,
                              hipStream_t stream)
{
  const float* x      = (const float*)d_in[0];
  const float* startw = (const float*)d_in[1];
  const float* startb = (const float*)d_in[2];
  const float* dilw   = (const float*)d_in[3];
  const float* dilb   = (const float*)d_in[4];
  const float* resw   = (const float*)d_in[5];
  const float* resb   = (const float*)d_in[6];
  const float* skipw  = (const float*)d_in[7];
  const float* skipb  = (const float*)d_in[8];
  const float* endw   = (const float*)d_in[9];
  const float* endb   = (const float*)d_in[10];

  unsigned short* H0 = (unsigned short*)d_ws;       // [8][8192][128] bf16 pos-major
  unsigned short* H1 = H0 + (size_t)8*L0*128;
  float* SK = (float*)(H1 + (size_t)8*L0*128);      // [8][4612][256] f32 pos-major
  unsigned short* Wd = (unsigned short*)(SK + (size_t)8*LFIN*256);
  unsigned short* Wr = Wd + (size_t)39*65536;
  unsigned short* Ws = Wr + (size_t)39*16384;
  unsigned short* We = Ws + (size_t)39*32768;
  float* SBS = (float*)(We + 16384);

  const int total = 39*65536 + 39*16384 + 39*32768 + 16384 + 256;
  wconv_kernel<<<(total + 255)/256, 256, 0, stream>>>(dilw, resw, skipw, endw, skipb,
                                                      Wd, Wr, Ws, We, SBS);
  start_kernel<<<dim3(L0/64, 8), 256, 0, stream>>>(x, startw, startb, H0);

  // groups: 5 layers with dils s*{1,2,4,8,16} (last group: 4 layers)
  static const int GI0[8] = {0, 5, 10, 15, 20, 25, 30, 35};
  static const int GNL[8] = {5, 5, 5, 5, 5, 5, 5, 4};
  static const int GS [8] = {1, 32, 1, 32, 1, 32, 1, 32};

  unsigned short* bufs[2] = {H0, H1};
  for (int g = 0; g < 8; ++g) {
    int i0 = GI0[g];
    group_mfma<<<dim3(1024), 256, 0, stream>>>(
        bufs[g & 1], bufs[(g & 1) ^ 1], SK,
        Wd + (size_t)i0*65536, dilb + (size_t)i0*256,
        Wr + (size_t)i0*16384, resb + (size_t)i0*128,
        Ws + (size_t)i0*32768,
        GS[g], GNL[g], i0, g ? 1 : 0, (g < 7) ? 1 : 0);
  }

  end_mfma<<<dim3((LFIN + 63)/64, 8), 256, 0, stream>>>(SK, We, SBS, endb, (float*)d_out);
}

// Round 9
// 1619.841 us; speedup vs baseline: 4.6571x; 1.2749x over previous
//
#include <hip/hip_runtime.h>

typedef __attribute__((ext_vector_type(8)))  short short8;
typedef __attribute__((ext_vector_type(4)))  float f32x4;
typedef __attribute__((ext_vector_type(16))) float f32x16;

#define L0    8192
#define LFIN  4612
#define PSKIP 3580   // L0 - LFIN

__device__ __forceinline__ unsigned short f2bf(float f) {
  unsigned u = __builtin_bit_cast(unsigned, f);
  u += 0x7fffu + ((u >> 16) & 1u);          // RNE
  return (unsigned short)(u >> 16);
}
__device__ __forceinline__ float bf2f(unsigned short h) {
  return __builtin_bit_cast(float, (unsigned)h << 16);
}

// ---------------- weight conversion f32 -> bf16 + skip-bias total (once per call) ----
// Wd layout: [layer][co 256][k 256], k = tap*128 + ci  (tap0 @ p-d, tap1 @ p)
__global__ __launch_bounds__(256) void wconv_kernel(
    const float* __restrict__ dw, const float* __restrict__ rw,
    const float* __restrict__ sw, const float* __restrict__ ew,
    const float* __restrict__ skb,
    unsigned short* __restrict__ Wd, unsigned short* __restrict__ Wr,
    unsigned short* __restrict__ Ws, unsigned short* __restrict__ We,
    float* __restrict__ SBS)
{
  int e = blockIdx.x * 256 + threadIdx.x;
  const int ND = 39*65536, NR = 39*16384, NS = 39*32768, NE = 16384;
  if (e < ND) {
    int i = e >> 16, r = e & 65535;
    int co = r >> 8, k = r & 255;
    int tap = k >> 7, ci = k & 127;
    Wd[e] = f2bf(dw[(((size_t)i*256 + co)*128 + ci)*2 + tap]);
  } else if ((e -= ND) < NR) {
    Wr[e] = f2bf(rw[e]);
  } else if ((e -= NR) < NS) {
    Ws[e] = f2bf(sw[e]);
  } else if ((e -= NS) < NE) {
    We[e] = f2bf(ew[e]);
  } else if ((e -= NE) < 256) {
    float s = 0.f;
    for (int i = 0; i < 39; ++i) s += skb[i*256 + e];
    SBS[e] = s;
  }
}

// ---------------- start: 1x1 conv 40 -> 128, position-major bf16 output ----------------
__global__ __launch_bounds__(256) void start_kernel(
    const float* __restrict__ x, const float* __restrict__ w,
    const float* __restrict__ b, unsigned short* __restrict__ H)
{
  __shared__ float xs[40][64];
  __shared__ float wl[128*41];
  const int tid = threadIdx.x;
  const int n = blockIdx.y;
  const int p0 = blockIdx.x * 64;

  for (int e = tid; e < 40*64; e += 256) {
    int ci = e >> 6, t = e & 63;
    xs[ci][t] = x[((size_t)n*40 + ci)*L0 + p0 + t];
  }
  for (int e = tid; e < 128*40; e += 256)
    wl[(e/40)*41 + (e%40)] = w[e];
  __syncthreads();

  const int c  = tid & 127;
  const int ph = tid >> 7;                 // 0..1
  const float bias = b[c];
  #pragma unroll 4
  for (int k = 0; k < 32; ++k) {
    int p = ph + 2*k;
    float acc = bias;
    #pragma unroll
    for (int ci = 0; ci < 40; ++ci)
      acc = fmaf(wl[c*41 + ci], xs[ci][p], acc);
    H[((size_t)n*L0 + p0 + p)*128 + c] = f2bf(acc);
  }
}

// ---------------- gate f/g -> bf16 into Gl row p ----------------
__device__ __forceinline__ void gate_write(char* Gl, const float* __restrict__ dbl,
    const f32x16& af, const f32x16& ag, int p, int w, int hi)
{
  #pragma unroll
  for (int q = 0; q < 4; ++q) {
    int rbase = 8*q + 4*hi;
    const float4 bf4 = *(const float4*)&dbl[32*w + rbase];
    const float4 bg4 = *(const float4*)&dbl[128 + 32*w + rbase];
    const float bfv[4] = {bf4.x, bf4.y, bf4.z, bf4.w};
    const float bgv[4] = {bg4.x, bg4.y, bg4.z, bg4.w};
    unsigned short gs[4];
    #pragma unroll
    for (int r = 0; r < 4; ++r) {
      float fv = af[4*q + r] + bfv[r];
      float gg = ag[4*q + r] + bgv[r];
      float th = 2.f * __builtin_amdgcn_rcpf(1.f + __expf(-2.f * fv)) - 1.f;
      float sg = __builtin_amdgcn_rcpf(1.f + __expf(-gg));
      gs[r] = f2bf(th * sg);
    }
    ushort4 gv; gv.x = gs[0]; gv.y = gs[1]; gv.z = gs[2]; gv.w = gs[3];
    int byte = ((p << 8) + ((32*w + rbase) << 1)) ^ ((p & 7) << 4);
    *(ushort4*)(Gl + byte) = gv;
  }
}

// ---------------- res writeback: racc + bias + residual -> Hl row sl ----------------
__device__ __forceinline__ void res_writeback(char* Hl, const float* __restrict__ rbl,
    const f32x16& racc, int sl, int w, int hi)
{
  #pragma unroll
  for (int q = 0; q < 4; ++q) {
    int co = 32*w + 8*q + 4*hi;
    const float4 rb4 = *(const float4*)&rbl[co];
    int hbyte = ((sl << 8) + (co << 1)) ^ ((sl & 7) << 4);
    ushort4 hv = *(const ushort4*)(Hl + hbyte);
    ushort4 hb;
    hb.x = f2bf(racc[4*q]   + rb4.x + bf2f(hv.x));
    hb.y = f2bf(racc[4*q+1] + rb4.y + bf2f(hv.y));
    hb.z = f2bf(racc[4*q+2] + rb4.z + bf2f(hv.z));
    hb.w = f2bf(racc[4*q+3] + rb4.w + bf2f(hv.w));
    *(ushort4*)(Hl + hbyte) = hb;
  }
}

// ---------------- fused group of NL dilated layers (dils = s*{1,2,4,8,16}) ----------
// Block owns 64 output positions strided by s, +32-slot strided halo: 96 slots in LDS.
// All inter-layer deps stay in the block (mod-s residue chains) -> NO global sync.
// Weights hoisted across the 3 slot-tiles: 2 global loads -> 6 MFMAs in GEMM1
// (R8 paid 1 load/MFMA via per-tile split; R7 hoisted but spilled under 128-cap).
// ALL accumulators are named scalars; cap = 256 VGPR (launch_bounds(256,1)).
__global__ __launch_bounds__(256, 1) void group_mfma(
    const unsigned short* __restrict__ Hin, unsigned short* __restrict__ Hout,
    float* __restrict__ SK,
    const unsigned short* __restrict__ Wd, const float* __restrict__ dilb,
    const unsigned short* __restrict__ Wr, const float* __restrict__ resb,
    const unsigned short* __restrict__ Ws,
    int s, int NL, int i0, int accum, int writeH)
{
  __shared__ __align__(16) unsigned short Hl[96*128];   // 24 KiB, row 256B swizzled
  __shared__ __align__(16) unsigned short Gl[96*128];   // 24 KiB

  const int tid = threadIdx.x;
  const int lb = blockIdx.x;
  const int n = lb & 7;                 // batch
  const int u = lb >> 3;                // 0..127
  const int r = (s == 1) ? 0 : (u & 31);
  const int t = (s == 1) ? u : (u >> 5);
  const int mbase = t*64 - 32;          // slot j -> m = mbase + j ; pos = r + s*m

  const int w = tid >> 6, lane = tid & 63;
  const int ln = lane & 31, hi = lane >> 5;

  const unsigned short* __restrict__ Hb = Hin + (size_t)n * L0 * 128;

  // ---- stage 96 slots from global H ----
  #pragma unroll
  for (int it = 0; it < 6; ++it) {
    int e = it*256 + tid;               // 96 rows x 16 threads
    int c8 = (e & 15) << 3;
    int j  = e >> 4;
    int gp = r + s * (mbase + j);
    if (gp < 0) gp = 0;                 // halo below valid region: bounded garbage, unused
    short8 v = *(const short8*)&Hb[(size_t)gp * 128 + c8];
    *(short8*)((char*)Hl + (((j << 8) + (c8 << 1)) ^ ((j & 7) << 4))) = v;
  }
  __syncthreads();

  const f32x16 fz16 = {0.f};
  f32x16 sk00 = fz16, sk01 = fz16, sk10 = fz16, sk11 = fz16;
  const bool doSkip = (r + s*(t*64 + 63)) >= PSKIP;

  #pragma unroll 1
  for (int l = 0; l < NL; ++l) {
    const int i = i0 + l;
    const int dil = 1 << l;             // dilation in slot space
    const unsigned short* __restrict__ Wdl = Wd + (size_t)l*65536;
    const float* dbl = dilb + l*256;

    // ---- GEMM1: weights hoisted across 3 tiles (2 loads -> 6 MFMAs per ks) ----
    const int r1_0 = ln,      r1_1 = 32 + ln,  r1_2 = 64 + ln;
    int rc_0 = r1_0 - dil; if (rc_0 < 0) rc_0 = 0;
    const int rc_1 = r1_1 - dil, rc_2 = r1_2 - dil;   // >= 0 always
    f32x16 af0 = fz16, af1 = fz16, af2 = fz16;
    f32x16 ag0 = fz16, ag1 = fz16, ag2 = fz16;
    #pragma unroll
    for (int ks = 0; ks < 16; ++ks) {
      int colb = (ks & 7)*32 + hi*16;
      short8 Af = *(const short8*)&Wdl[(size_t)(32*w + ln)*256 + ks*16 + hi*8];
      short8 Ag = *(const short8*)&Wdl[(size_t)(128 + 32*w + ln)*256 + ks*16 + hi*8];
      int row0 = (ks < 8) ? rc_0 : r1_0;
      int row1 = (ks < 8) ? rc_1 : r1_1;
      int row2 = (ks < 8) ? rc_2 : r1_2;
      short8 B0 = *(const short8*)((const char*)Hl + ((row0 << 8) + (colb ^ ((row0 & 7) << 4))));
      short8 B1 = *(const short8*)((const char*)Hl + ((row1 << 8) + (colb ^ ((row1 & 7) << 4))));
      short8 B2 = *(const short8*)((const char*)Hl + ((row2 << 8) + (colb ^ ((row2 & 7) << 4))));
      af0 = __builtin_amdgcn_mfma_f32_32x32x16_bf16(Af, B0, af0, 0, 0, 0);
      ag0 = __builtin_amdgcn_mfma_f32_32x32x16_bf16(Ag, B0, ag0, 0, 0, 0);
      af1 = __builtin_amdgcn_mfma_f32_32x32x16_bf16(Af, B1, af1, 0, 0, 0);
      ag1 = __builtin_amdgcn_mfma_f32_32x32x16_bf16(Ag, B1, ag1, 0, 0, 0);
      af2 = __builtin_amdgcn_mfma_f32_32x32x16_bf16(Af, B2, af2, 0, 0, 0);
      ag2 = __builtin_amdgcn_mfma_f32_32x32x16_bf16(Ag, B2, ag2, 0, 0, 0);
    }
    gate_write((char*)Gl, dbl, af0, ag0, r1_0, w, hi);
    gate_write((char*)Gl, dbl, af1, ag1, r1_1, w, hi);
    gate_write((char*)Gl, dbl, af2, ag2, r1_2, w, hi);
    __syncthreads();                    // Gl complete; all Hl reads of GEMM1 done

    // ---- skip GEMM on own tiles (slots 32..95) -> persistent named sk regs ----
    if (doSkip) {
      const unsigned short* __restrict__ Wsl = Ws + (size_t)l*32768;
      const int rB0 = 32 + ln, rB1 = 64 + ln;
      #pragma unroll
      for (int ks = 0; ks < 8; ++ks) {
        int colb = ks*32 + hi*16;
        short8 A0 = *(const short8*)&Wsl[(size_t)(32*w + ln)*128 + ks*16 + hi*8];
        short8 A1 = *(const short8*)&Wsl[(size_t)(128 + 32*w + ln)*128 + ks*16 + hi*8];
        short8 B0 = *(const short8*)((const char*)Gl +
                      ((rB0 << 8) + (colb ^ ((rB0 & 7) << 4))));
        short8 B1 = *(const short8*)((const char*)Gl +
                      ((rB1 << 8) + (colb ^ ((rB1 & 7) << 4))));
        sk00 = __builtin_amdgcn_mfma_f32_32x32x16_bf16(A0, B0, sk00, 0, 0, 0);
        sk01 = __builtin_amdgcn_mfma_f32_32x32x16_bf16(A0, B1, sk01, 0, 0, 0);
        sk10 = __builtin_amdgcn_mfma_f32_32x32x16_bf16(A1, B0, sk10, 0, 0, 0);
        sk11 = __builtin_amdgcn_mfma_f32_32x32x16_bf16(A1, B1, sk11, 0, 0, 0);
      }
    }

    // ---- res GEMM: weights hoisted across 3 tiles; update Hl in place ----
    if (i < 38) {
      const unsigned short* __restrict__ Wrl = Wr + (size_t)l*16384;
      const float* rbl = resb + l*128;
      f32x16 rk0 = fz16, rk1 = fz16, rk2 = fz16;
      #pragma unroll
      for (int ks = 0; ks < 8; ++ks) {
        int colb = ks*32 + hi*16;
        short8 A = *(const short8*)&Wrl[(size_t)(32*w + ln)*128 + ks*16 + hi*8];
        short8 B0 = *(const short8*)((const char*)Gl +
                      ((r1_0 << 8) + (colb ^ ((r1_0 & 7) << 4))));
        short8 B1 = *(const short8*)((const char*)Gl +
                      ((r1_1 << 8) + (colb ^ ((r1_1 & 7) << 4))));
        short8 B2 = *(const short8*)((const char*)Gl +
                      ((r1_2 << 8) + (colb ^ ((r1_2 & 7) << 4))));
        rk0 = __builtin_amdgcn_mfma_f32_32x32x16_bf16(A, B0, rk0, 0, 0, 0);
        rk1 = __builtin_amdgcn_mfma_f32_32x32x16_bf16(A, B1, rk1, 0, 0, 0);
        rk2 = __builtin_amdgcn_mfma_f32_32x32x16_bf16(A, B2, rk2, 0, 0, 0);
      }
      if (l < NL-1)                     // halo tile not needed after last sub-layer
        res_writeback((char*)Hl, rbl, rk0, r1_0, w, hi);
      res_writeback((char*)Hl, rbl, rk1, r1_1, w, hi);
      res_writeback((char*)Hl, rbl, rk2, r1_2, w, hi);
    }
    __syncthreads();                    // Hl ready for next sub-layer; Gl reads done
  }

  // ---- write own 64 slots of final H to global (not needed after last group) ----
  if (writeH) {
    unsigned short* __restrict__ Ho = Hout + (size_t)n * L0 * 128;
    #pragma unroll
    for (int it = 0; it < 4; ++it) {
      int e = it*256 + tid;             // 64 rows x 16 threads
      int c8 = (e & 15) << 3;
      int j  = 32 + (e >> 4);
      int gp = r + s * (mbase + j);     // in [0, 8191] for own slots
      short8 v = *(const short8*)((const char*)Hl +
                   (((j << 8) + (c8 << 1)) ^ ((j & 7) << 4)));
      *(short8*)&Ho[(size_t)gp * 128 + c8] = v;
    }
  }

  // ---- SK read-modify-write, once per group ----
  if (doSkip) {
    float* SKn = SK + (size_t)n * LFIN * 256;
    #pragma unroll
    for (int nb = 0; nb < 2; ++nb) {
      int sl = 32 + nb*32 + ln;
      int p = r + s * (mbase + sl);
      if (p >= PSKIP) {
        int pi = p - PSKIP;
        #pragma unroll
        for (int q = 0; q < 4; ++q) {
          const f32x16& a0 = nb ? sk01 : sk00;
          const f32x16& a1 = nb ? sk11 : sk10;
          {
            int co = 32*w + 8*q + 4*hi;
            float* dst = &SKn[(size_t)pi * 256 + co];
            float4 v = make_float4(a0[4*q], a0[4*q+1], a0[4*q+2], a0[4*q+3]);
            if (accum) {
              float4 o = *(const float4*)dst;
              v.x += o.x; v.y += o.y; v.z += o.z; v.w += o.w;
            }
            *(float4*)dst = v;
          }
          {
            int co = 32*w + 128 + 8*q + 4*hi;
            float* dst = &SKn[(size_t)pi * 256 + co];
            float4 v = make_float4(a1[4*q], a1[4*q+1], a1[4*q+2], a1[4*q+3]);
            if (accum) {
              float4 o = *(const float4*)dst;
              v.x += o.x; v.y += o.y; v.z += o.z; v.w += o.w;
            }
            *(float4*)dst = v;
          }
        }
      }
    }
  }
}

// ---------------- end: relu(skip + total skip-bias) + 1x1 conv 256 -> 64 ----------------
__global__ __launch_bounds__(256) void end_mfma(
    const float* __restrict__ SK, const unsigned short* __restrict__ We,
    const float* __restrict__ SBS, const float* __restrict__ eb,
    float* __restrict__ out)
{
  __shared__ unsigned short sl[64*256];
  const int tid = threadIdx.x;
  const int n = blockIdx.y;
  const int p0 = blockIdx.x * 64;
  const float* __restrict__ SKn = SK + (size_t)n * LFIN * 256;

  #pragma unroll
  for (int it = 0; it < 16; ++it) {
    int e = it * 256 + tid;
    int c4 = (e & 63) << 2;
    int p  = e >> 6;
    int gp = p0 + p; if (gp > LFIN - 1) gp = LFIN - 1;
    float4 v = *(const float4*)&SKn[(size_t)gp * 256 + c4];
    float4 s4 = *(const float4*)&SBS[c4];
    ushort4 h;
    h.x = f2bf(fmaxf(v.x + s4.x, 0.f)); h.y = f2bf(fmaxf(v.y + s4.y, 0.f));
    h.z = f2bf(fmaxf(v.z + s4.z, 0.f)); h.w = f2bf(fmaxf(v.w + s4.w, 0.f));
    int byte = ((p << 9) + (c4 << 1)) ^ ((p & 7) << 4);
    *(ushort4*)((char*)sl + byte) = h;
  }
  __syncthreads();

  const int w  = tid >> 6, lane = tid & 63;
  const int lr = lane & 15, lg = lane >> 4;
  const f32x4 fz = {0.f, 0.f, 0.f, 0.f};
  f32x4 acc[4] = {fz, fz, fz, fz};

  #pragma unroll
  for (int ks = 0; ks < 8; ++ks) {
    short8 A = *(const short8*)&We[(size_t)(16*w + lr) * 256 + ks*32 + lg*8];
    #pragma unroll
    for (int nb = 0; nb < 4; ++nb) {
      int p = nb * 16 + lr;
      int byte = ((p << 9) + ((ks*32 + lg*8) << 1)) ^ ((p & 7) << 4);
      short8 B = *(const short8*)((const char*)sl + byte);
      acc[nb] = __builtin_amdgcn_mfma_f32_16x16x32_bf16(A, B, acc[nb], 0, 0, 0);
    }
  }
  #pragma unroll
  for (int nb = 0; nb < 4; ++nb) {
    int p = p0 + nb*16 + lr;
    if (p < LFIN) {
      #pragma unroll
      for (int r = 0; r < 4; ++r) {
        int co = 16*w + lg*4 + r;
        out[((size_t)n*64 + co) * LFIN + p] = acc[nb][r] + eb[co];
      }
    }
  }
}

// ---------------- host ----------------
extern "C" void kernel_launch(void* const* d_in, const int* in_sizes, int n_in,
                              void* d_out, int out_size, void* d_ws, size_t ws_size,
                              hipStream_t stream)
{
  const float* x      = (const float*)d_in[0];
  const float* startw = (const float*)d_in[1];
  const float* startb = (const float*)d_in[2];
  const float* dilw   = (const float*)d_in[3];
  const float* dilb   = (const float*)d_in[4];
  const float* resw   = (const float*)d_in[5];
  const float* resb   = (const float*)d_in[6];
  const float* skipw  = (const float*)d_in[7];
  const float* skipb  = (const float*)d_in[8];
  const float* endw   = (const float*)d_in[9];
  const float* endb   = (const float*)d_in[10];

  unsigned short* H0 = (unsigned short*)d_ws;       // [8][8192][128] bf16 pos-major
  unsigned short* H1 = H0 + (size_t)8*L0*128;
  float* SK = (float*)(H1 + (size_t)8*L0*128);      // [8][4612][256] f32 pos-major
  unsigned short* Wd = (unsigned short*)(SK + (size_t)8*LFIN*256);
  unsigned short* Wr = Wd + (size_t)39*65536;
  unsigned short* Ws = Wr + (size_t)39*16384;
  unsigned short* We = Ws + (size_t)39*32768;
  float* SBS = (float*)(We + 16384);

  const int total = 39*65536 + 39*16384 + 39*32768 + 16384 + 256;
  wconv_kernel<<<(total + 255)/256, 256, 0, stream>>>(dilw, resw, skipw, endw, skipb,
                                                      Wd, Wr, Ws, We, SBS);
  start_kernel<<<dim3(L0/64, 8), 256, 0, stream>>>(x, startw, startb, H0);

  // groups: 5 layers with dils s*{1,2,4,8,16} (last group: 4 layers)
  static const int GI0[8] = {0, 5, 10, 15, 20, 25, 30, 35};
  static const int GNL[8] = {5, 5, 5, 5, 5, 5, 5, 4};
  static const int GS [8] = {1, 32, 1, 32, 1, 32, 1, 32};

  unsigned short* bufs[2] = {H0, H1};
  for (int g = 0; g < 8; ++g) {
    int i0 = GI0[g];
    group_mfma<<<dim3(1024), 256, 0, stream>>>(
        bufs[g & 1], bufs[(g & 1) ^ 1], SK,
        Wd + (size_t)i0*65536, dilb + (size_t)i0*256,
        Wr + (size_t)i0*16384, resb + (size_t)i0*128,
        Ws + (size_t)i0*32768,
        GS[g], GNL[g], i0, g ? 1 : 0, (g < 7) ? 1 : 0);
  }

  end_mfma<<<dim3((LFIN + 63)/64, 8), 256, 0, stream>>>(SK, We, SBS, endb, (float*)d_out);
}